// Round 3
// baseline (42.735 us; speedup 1.0000x reference)
//
#include <hip/hip_runtime.h>

// Problem constants (from reference setup_inputs)
constexpr int Bn = 256;
constexpr int Nn = 16384;
constexpr int Hh = 96;
constexpr int Ww = 96;

constexpr int THREADS = 1024;
constexpr int PS2  = 100;           // float2 entries per padded row
constexpr int ROWS = 100;           // padded rows
constexpr int ENT  = ROWS * PS2;    // 10000 float2 entries per map
constexpr int PER_THREAD = Nn / THREADS;   // 16 corners per thread

// Duplicated-pair layout: entry (py,px) = (P[py-2][px-2], P[py-2][px-1]),
// zero outside the 96x96 interior. Every bilinear gather is an aligned
// ds_read_b64 fetching two horizontally-adjacent pixels.
__global__ __launch_bounds__(THREADS, 4)
void geo_kernel(const float* __restrict__ corners,
                const float* __restrict__ edge,
                const float* __restrict__ mask,
                double* __restrict__ acc,      // [0]=edge sum, [1]=mask sum, [2]=counter
                float* __restrict__ out)
{
    __shared__ float2 sE[ENT];
    __shared__ float2 sM[ENT];
    __shared__ float redE[THREADS / 64];
    __shared__ float redM[THREADS / 64];

    const int b = blockIdx.x;
    const int tid = threadIdx.x;

    // --- batch-load this thread's 16 corners (independent coalesced loads) ---
    const float2* c2 = (const float2*)(corners + (size_t)b * Nn * 2);
    float2 cc[PER_THREAD];
#pragma unroll
    for (int j = 0; j < PER_THREAD; ++j)
        cc[j] = c2[tid + j * THREADS];

    // --- zero ONLY the borders (interior is fully overwritten below) ---
    {
        const float2 z2 = make_float2(0.f, 0.f);
        // top 2 rows + bottom 2 rows: 200 entries each end, per map
        for (int i = tid; i < 200; i += THREADS) {
            sE[i] = z2;            sM[i] = z2;
            sE[ENT - 200 + i] = z2; sM[ENT - 200 + i] = z2;
        }
        // left/right 2-entry strips of the 96 interior rows
        for (int i = tid; i < 96 * 4; i += THREADS) {
            int r = i >> 2;
            int k = i & 3;
            int c = (k < 2) ? k : (96 + k);     // {0,1,98,99}
            int idx = (r + 2) * PS2 + c;
            sE[idx] = z2; sM[idx] = z2;
        }
    }
    // no sync needed yet: fill below touches disjoint interior entries except
    // odd-col writes into cols 1 and 97.. wait: col 1 is border (zeroed) and
    // also odd-left target of j=0 -> overlap. Keep the sync for safety.
    __syncthreads();

    // --- fill interior with duplicated pairs ---
    {
        const float2* eg = (const float2*)(edge + (size_t)b * Hh * Ww);
        const float2* mg = (const float2*)(mask + (size_t)b * Hh * Ww);
        for (int i = tid; i < (Ww / 2) * Hh; i += THREADS) {
            int r = i / (Ww / 2);
            int j = i - r * (Ww / 2);
            int row = (r + 2) * PS2;
            float2 ve = eg[i];
            sE[row + 2 * j + 2]   = ve;     // even entry (I[2j], I[2j+1])
            sE[row + 2 * j + 1].y = ve.x;   // odd-left  .y = I[2j]
            sE[row + 2 * j + 3].x = ve.y;   // odd-right .x = I[2j+1]
            float2 vm = mg[i];
            sM[row + 2 * j + 2]   = vm;
            sM[row + 2 * j + 1].y = vm.x;
            sM[row + 2 * j + 3].x = vm.y;
        }
    }
    __syncthreads();

    // --- per-corner work: fully unrolled, deep LDS pipelining ---
    float eAcc = 0.f, mAcc = 0.f;
#pragma unroll
    for (int j = 0; j < PER_THREAD; ++j) {
        float2 c = cc[j];
        // ix = ((gx+1)*W - 1)*0.5 with gx = 2*cx - 1  ==>  ix = 96*cx - 0.5
        float ix = fmaf(c.x, 96.f, -0.5f);
        float iy = fmaf(c.y, 96.f, -0.5f);
        float x0f = floorf(ix), y0f = floorf(iy);
        float wx = ix - x0f, wy = iy - y0f;
        int x0 = (int)x0f, y0 = (int)y0f;

        // edge: 4x4 patch rows y0-1..y0+2, cols x0-1..x0+2
        int cb = (y0 + 1) * PS2 + (x0 + 1);
        float2 a0 = sE[cb];
        float2 d0 = sE[cb + 2];
        float2 a1 = sE[cb + PS2];
        float2 d1 = sE[cb + PS2 + 2];
        float2 a2 = sE[cb + 2 * PS2];
        float2 d2 = sE[cb + 2 * PS2 + 2];
        float2 a3 = sE[cb + 3 * PS2];
        float2 d3 = sE[cb + 3 * PS2 + 2];
        // mask: 2x2 at (x0..x0+1, y0..y0+1)
        int mb = (y0 + 2) * PS2 + (x0 + 2);
        float2 m0 = sM[mb];
        float2 m1 = sM[mb + PS2];

        float h[4][3];
        h[0][0] = fmaf(wx, a0.y - a0.x, a0.x);
        h[0][1] = fmaf(wx, d0.x - a0.y, a0.y);
        h[0][2] = fmaf(wx, d0.y - d0.x, d0.x);
        h[1][0] = fmaf(wx, a1.y - a1.x, a1.x);
        h[1][1] = fmaf(wx, d1.x - a1.y, a1.y);
        h[1][2] = fmaf(wx, d1.y - d1.x, d1.x);
        h[2][0] = fmaf(wx, a2.y - a2.x, a2.x);
        h[2][1] = fmaf(wx, d2.x - a2.y, a2.y);
        h[2][2] = fmaf(wx, d2.y - d2.x, d2.x);
        h[3][0] = fmaf(wx, a3.y - a3.x, a3.x);
        h[3][1] = fmaf(wx, d3.x - a3.y, a3.y);
        h[3][2] = fmaf(wx, d3.y - d3.x, d3.x);

        float best = fmaf(wy, h[1][0] - h[0][0], h[0][0]);
#pragma unroll
        for (int r = 0; r < 3; ++r) {
#pragma unroll
            for (int k = 0; k < 3; ++k) {
                if (r == 0 && k == 0) continue;
                float s = fmaf(wy, h[r + 1][k] - h[r][k], h[r][k]);
                best = fmaxf(best, s);
            }
        }
        eAcc += best;

        float t = fmaf(wx, m0.y - m0.x, m0.x);
        float u = fmaf(wx, m1.y - m1.x, m1.x);
        float mm = fmaf(wy, u - t, t);
        float dd = mm - 0.5f;
        mAcc = fmaf(dd, dd, mAcc);
    }

    // --- reduce: wave shuffle, cross-wave via LDS ---
#pragma unroll
    for (int off = 32; off > 0; off >>= 1) {
        eAcc += __shfl_xor(eAcc, off);
        mAcc += __shfl_xor(mAcc, off);
    }
    const int wv = tid >> 6;
    const int ln = tid & 63;
    if (ln == 0) { redE[wv] = eAcc; redM[wv] = mAcc; }
    __syncthreads();

    if (tid == 0) {
        float e = 0.f, m = 0.f;
#pragma unroll
        for (int w = 0; w < THREADS / 64; ++w) { e += redE[w]; m += redM[w]; }
        atomicAdd(&acc[0], (double)e);
        atomicAdd(&acc[1], (double)m);
        __threadfence();
        unsigned old = atomicAdd((unsigned*)&acc[2], 1u);
        if (old == (unsigned)(gridDim.x - 1)) {
            double se = atomicAdd(&acc[0], 0.0);
            double sm = atomicAdd(&acc[1], 0.0);
            const double inv = 1.0 / (double)((long long)Bn * (long long)Nn);
            double edge_loss = 1.0 - se * inv;
            double mask_loss = sm * inv;
            out[0] = (float)(edge_loss + 2.0 * mask_loss);
        }
    }
}

extern "C" void kernel_launch(void* const* d_in, const int* in_sizes, int n_in,
                              void* d_out, int out_size, void* d_ws, size_t ws_size,
                              hipStream_t stream)
{
    const float* corners = (const float*)d_in[0];
    const float* edge    = (const float*)d_in[1];
    const float* mask    = (const float*)d_in[2];
    float* out  = (float*)d_out;
    double* acc = (double*)d_ws;

    hipMemsetAsync(acc, 0, 32, stream);   // 2 doubles + counter
    geo_kernel<<<Bn, THREADS, 0, stream>>>(corners, edge, mask, acc, out);
}